// Round 8
// baseline (246.336 us; speedup 1.0000x reference)
//
#include <hip/hip_runtime.h>

#define B_   2
#define N_   32768
#define M_   4096
#define C_   128
#define OUT_ 128
#define IN_  131

#define NSPLIT 16
#define MCHUNK (M_ / NSPLIT)     // 256 points per split
#define NQ     (B_ * N_)         // 65536 total queries
#define NNBLK  ((NQ / 1024) * NSPLIT)   // 1024 NN blocks
#define PREBLK (B_ * M_ / 128)          // 64 pre-GEMM blocks
#define QBLK   64                       // tail queries per block

typedef float f32x2 __attribute__((ext_vector_type(2)));

// Packed fp32 (VOP3P, CDNA4). Each is IEEE round-to-nearest per component —
// bit-identical to the scalar __fmul_rn/__fadd_rn/__fmaf_rn it replaces.
#define PK_MUL(d,a,b)   asm("v_pk_mul_f32 %0, %1, %2" : "=v"(d) : "v"(a), "v"(b))
#define PK_ADD(d,a,b)   asm("v_pk_add_f32 %0, %1, %2" : "=v"(d) : "v"(a), "v"(b))
#define PK_FMA(d,a,b,c) asm("v_pk_fma_f32 %0, %1, %2, %3" : "=v"(d) : "v"(a), "v"(b), "v"(c))

// ---------------------------------------------------------------------------
// K1 (fused front): blocks [0,1024) = split 3-NN; blocks [1024,1088) =
// pre-GEMM. THIS ROUND'S ONLY CHANGE: the NN distance evaluation is packed
// 2-points-per-instruction via v_pk_* (SoA LDS staging, ds_read_b64 pairs).
// The serial top-3 update keeps its exact scalar sequence and j, j+1 order —
// identical rounding and tie semantics. Update ops untouched.
// ---------------------------------------------------------------------------
#define NN_DECL(X)                                                        \
    f32x2 x0##X, x1##X, x2##X, xx##X;                                     \
    float bd0##X = 1e30f, bd1##X = 1e30f, bd2##X = 1e30f;                 \
    int   bi0##X = 0,     bi1##X = 0,     bi2##X = 0;

#define NN_LOAD(X, QQ) {                                                  \
    const int qi = q0 + (QQ) * 256 + t;                                   \
    float a0 = x[(size_t)qi*3+0];                                         \
    float a1 = x[(size_t)qi*3+1];                                         \
    float a2 = x[(size_t)qi*3+2];                                         \
    float aa = __fadd_rn(__fadd_rn(__fmul_rn(a0,a0),                      \
                                   __fmul_rn(a1,a1)),                     \
                         __fmul_rn(a2,a2));                               \
    x0##X = (f32x2){a0,a0}; x1##X = (f32x2){a1,a1};                       \
    x2##X = (f32x2){a2,a2}; xx##X = (f32x2){aa,aa}; }

// packed distance for points (j, j+1):
//   dot = ((x0*sx + x1*sy) + x2*sz);  d2 = (-2*dot + xx) + ss
// — same op sequence as the scalar version, per component.
#define NN_PKD2(X)                                                        \
    f32x2 d2##X; {                                                        \
    f32x2 t0, t1, t2;                                                     \
    PK_MUL(t0, x0##X, sx2);                                               \
    PK_MUL(t1, x1##X, sy2);                                               \
    PK_MUL(t2, x2##X, sz2);                                               \
    PK_ADD(t0, t0, t1);                                                   \
    PK_ADD(t0, t0, t2);                                                   \
    PK_FMA(t0, m2c, t0, xx##X);                                           \
    PK_ADD(d2##X, t0, ss2); }

// serial top-3 update — character-identical semantics to the proven NN_STEP
#define NN_UPD(X, D2, MM) {                                               \
    const float d2u = (D2);                                               \
    const float k0 = bd0##X, k1 = bd1##X, k2 = bd2##X;                    \
    const bool c0 = d2u < k0, c1 = d2u < k1, c2 = d2u < k2;               \
    bi2##X = c1 ? bi1##X : (c2 ? (MM) : bi2##X);                          \
    bi1##X = c0 ? bi0##X : (c1 ? (MM) : bi1##X);                          \
    bi0##X = c0 ? (MM) : bi0##X;                                          \
    bd0##X = fminf(k0, d2u);                                              \
    bd1##X = __builtin_amdgcn_fmed3f(d2u, k0, k1);                        \
    bd2##X = __builtin_amdgcn_fmed3f(d2u, k1, k2); }

#define NN_STORE(X, QQ) {                                                 \
    const int qi = q0 + (QQ) * 256 + t;                                   \
    part_d[(size_t)split * NQ + qi] =                                     \
        make_float4(bd0##X, bd1##X, bd2##X, 0.f);                         \
    part_i[(size_t)split * NQ + qi] =                                     \
        make_ushort4((unsigned short)bi0##X, (unsigned short)bi1##X,      \
                     (unsigned short)bi2##X, 0); }

__global__ __launch_bounds__(256, 4) void fused_front_kernel(const float* __restrict__ x,
                                                             const float* __restrict__ sx,
                                                             float4* __restrict__ part_d,
                                                             ushort4* __restrict__ part_i,
                                                             const float* __restrict__ features,
                                                             const float* __restrict__ w1,
                                                             float* __restrict__ G) {
    __shared__ __align__(16) float sxx[MCHUNK];   // 1 KB  (NN path, SoA)
    __shared__ __align__(16) float sxy[MCHUNK];   // 1 KB
    __shared__ __align__(16) float sxz[MCHUNK];   // 1 KB
    __shared__ __align__(16) float sss[MCHUNK];   // 1 KB
    __shared__ float  sI[16][132];    // 8.25 KB (pre path)
    __shared__ float  sW[16][132];    // 8.25 KB (pre path)
    const int tid = threadIdx.x;

    if (blockIdx.x < NNBLK) {
        // ---------------- NN path ----------------
        const int split = blockIdx.x & (NSPLIT - 1);
        const int qb    = blockIdx.x >> 4;
        const int q0    = qb * 1024;
        const int b     = q0 >> 15;                     // N_=32768
        const int t     = tid;

        {   // stage split points as SoA (|s|^2 in reference rounding order)
            const float* sp = sx + ((size_t)b * M_ + split * MCHUNK + t) * 3;
            float s0 = sp[0], s1 = sp[1], s2 = sp[2];
            float ss = __fadd_rn(__fadd_rn(__fmul_rn(s0,s0), __fmul_rn(s1,s1)),
                                 __fmul_rn(s2,s2));
            sxx[t] = s0; sxy[t] = s1; sxz[t] = s2; sss[t] = ss;
        }
        __syncthreads();

        NN_DECL(A) NN_DECL(B) NN_DECL(C) NN_DECL(D)
        NN_LOAD(A, 0) NN_LOAD(B, 1) NN_LOAD(C, 2) NN_LOAD(D, 3)
        const f32x2 m2c = (f32x2){-2.0f, -2.0f};

        const int m_base = split * MCHUNK;
        #pragma unroll 2
        for (int j = 0; j < MCHUNK; j += 2) {
            const f32x2 sx2 = *(const f32x2*)&sxx[j];   // ds_read_b64 pair
            const f32x2 sy2 = *(const f32x2*)&sxy[j];
            const f32x2 sz2 = *(const f32x2*)&sxz[j];
            const f32x2 ss2 = *(const f32x2*)&sss[j];
            const int m = m_base + j;
            NN_PKD2(A) NN_PKD2(B) NN_PKD2(C) NN_PKD2(D)
            NN_UPD(A, d2A.x, m) NN_UPD(A, d2A.y, m+1)
            NN_UPD(B, d2B.x, m) NN_UPD(B, d2B.y, m+1)
            NN_UPD(C, d2C.x, m) NN_UPD(C, d2C.y, m+1)
            NN_UPD(D, d2D.x, m) NN_UPD(D, d2D.y, m+1)
        }

        NN_STORE(A, 0) NN_STORE(B, 1) NN_STORE(C, 2) NN_STORE(D, 3)
    } else {
        // ---------------- pre-GEMM path (unchanged arithmetic) ---------------
        const int row0 = (blockIdx.x - NNBLK) * 128;
        const int tr   = tid & 15;
        const int tc   = tid >> 4;
        float acc[8][8] = {};

        for (int kc = 0; kc < 8; ++kc) {
            #pragma unroll
            for (int j = 0; j < 2; ++j) {
                int id  = j * 256 + tid;
                int row = id >> 2, kq = id & 3;
                float4 g = ((const float4*)features)[(size_t)(row0 + row) * 32 + kc * 4 + kq];
                sI[kq*4+0][row] = g.x; sI[kq*4+1][row] = g.y;
                sI[kq*4+2][row] = g.z; sI[kq*4+3][row] = g.w;
            }
            {
                int o = tid >> 1, kk0 = (tid & 1) * 8;
                #pragma unroll
                for (int kk = 0; kk < 8; ++kk)
                    sW[kk0+kk][o] = w1[(size_t)o * IN_ + 3 + kc*16 + kk0 + kk];
            }
            __syncthreads();
            #pragma unroll
            for (int kk = 0; kk < 16; ++kk) {
                float4 a0 = *(const float4*)&sI[kk][tr*8];
                float4 a1 = *(const float4*)&sI[kk][tr*8+4];
                float4 c0 = *(const float4*)&sW[kk][tc*8];
                float4 c1 = *(const float4*)&sW[kk][tc*8+4];
                float av[8] = {a0.x,a0.y,a0.z,a0.w,a1.x,a1.y,a1.z,a1.w};
                float bv[8] = {c0.x,c0.y,c0.z,c0.w,c1.x,c1.y,c1.z,c1.w};
                #pragma unroll
                for (int i = 0; i < 8; ++i)
                    #pragma unroll
                    for (int j = 0; j < 8; ++j)
                        acc[i][j] = fmaf(av[i], bv[j], acc[i][j]);
            }
            __syncthreads();
        }

        #pragma unroll
        for (int i = 0; i < 8; ++i) {
            int r = row0 + tr*8 + i;
            float4 o0 = make_float4(acc[i][0], acc[i][1], acc[i][2], acc[i][3]);
            float4 o1 = make_float4(acc[i][4], acc[i][5], acc[i][6], acc[i][7]);
            ((float4*)G)[(size_t)r * 32 + tc*2 + 0] = o0;
            ((float4*)G)[(size_t)r * 32 + tc*2 + 1] = o1;
        }
    }
}

// ---------------------------------------------------------------------------
// K3 (fused tail): FROZEN — byte-identical to round 5 (the 231.0us config).
// Three pipeline restructures (R1/R2/R7) all lost to this plain loop; the
// implicit wave-overlap at 4-5 blocks/CU already captures the latency hiding.
// ---------------------------------------------------------------------------
__global__ __launch_bounds__(256) void fused_tail_kernel(const float4* __restrict__ part_d,
                                                         const ushort4* __restrict__ part_i,
                                                         const float* __restrict__ G,
                                                         const float* __restrict__ x,
                                                         const float* __restrict__ w1,
                                                         const float* __restrict__ b1,
                                                         const float* __restrict__ w2,
                                                         const float* __restrict__ b2,
                                                         float* __restrict__ out) {
    __shared__ float  sA[16][68];     // H chunk [k][row]   4.25 KB
    __shared__ float  sW[16][132];    // w2 chunk [k][out]  8.25 KB
    __shared__ int4   sIdx[QBLK];     // merged top-3 per query
    __shared__ float4 sX[QBLK];       // query coords
    __shared__ float4 sWX[128];       // (wx0,wx1,wx2,b1) per channel
    const int row0 = blockIdx.x * QBLK;
    const int tid  = threadIdx.x;
    const int tr   = tid & 7;         // row-group: rows tr*8 .. tr*8+7
    const int tc   = tid >> 3;        // col-group: cols tc*4 .. tc*4+3
    const int b    = row0 >> 15;

    // ---- Phase 0: merge (threads 0-63) || stage w1-xyz table (64-191) ----
    if (tid < QBLK) {
        const int q = row0 + tid;
        float b0 = 1e30f, b1v = 1e30f, b2v = 1e30f;
        int   i0 = 0,     i1 = 0,      i2 = 0;
        #pragma unroll
        for (int s = 0; s < NSPLIT; ++s) {
            float4  d = part_d[(size_t)s * NQ + q];
            ushort4 u = part_i[(size_t)s * NQ + q];
            const int ux = u.x, uy = u.y, uz = u.z;
            if (d.x < b2v) { if (d.x < b1v) { b2v=b1v; i2=i1;
                if (d.x < b0) { b1v=b0; i1=i0; b0=d.x; i0=ux; }
                else          { b1v=d.x; i1=ux; } } else { b2v=d.x; i2=ux; } }
            if (d.y < b2v) { if (d.y < b1v) { b2v=b1v; i2=i1;
                if (d.y < b0) { b1v=b0; i1=i0; b0=d.y; i0=uy; }
                else          { b1v=d.y; i1=uy; } } else { b2v=d.y; i2=uy; } }
            if (d.z < b2v) { if (d.z < b1v) { b2v=b1v; i2=i1;
                if (d.z < b0) { b1v=b0; i1=i0; b0=d.z; i0=uz; }
                else          { b1v=d.z; i1=uz; } } else { b2v=d.z; i2=uz; } }
        }
        sIdx[tid] = make_int4(i0, i1, i2, 0);
        const float* xp = x + (size_t)q * 3;
        sX[tid] = make_float4(xp[0], xp[1], xp[2], 0.f);
    } else if (tid < QBLK + 128) {
        const int c = tid - QBLK;
        sWX[c] = make_float4(w1[(size_t)c*IN_+0], w1[(size_t)c*IN_+1],
                             w1[(size_t)c*IN_+2], b1[c]);
    }
    __syncthreads();

    // ---- kc loop: build H chunk in LDS + stage w2 chunk, then FMA core ----
    const float4* gb = (const float4*)G + (size_t)b * M_ * 32;
    float acc[8][4] = {};
    for (int kc = 0; kc < 8; ++kc) {
        {   // H build: one (row, kq) slot per thread (row = tid>>2 in [0,64))
            const int row = tid >> 2, kq = tid & 3;
            const int c4 = kc * 4 + kq;          // channel-group [0,32)
            int4 v = sIdx[row];
            float4 a = gb[(size_t)v.x * 32 + c4];
            float4 e = gb[(size_t)v.y * 32 + c4];
            float4 f = gb[(size_t)v.z * 32 + c4];
            float4 xr = sX[row];
            float4 w0  = sWX[c4*4+0], w1v = sWX[c4*4+1];
            float4 w2v = sWX[c4*4+2], w3  = sWX[c4*4+3];
            float h;
            h = ((a.x + e.x) + f.x) * (1.0f/3.0f);
            h = fmaf(w0.x,xr.x, fmaf(w0.y,xr.y, fmaf(w0.z,xr.z, h))) + w0.w;
            sA[kq*4+0][row] = h > 0.0f ? h : 0.0f;
            h = ((a.y + e.y) + f.y) * (1.0f/3.0f);
            h = fmaf(w1v.x,xr.x, fmaf(w1v.y,xr.y, fmaf(w1v.z,xr.z, h))) + w1v.w;
            sA[kq*4+1][row] = h > 0.0f ? h : 0.0f;
            h = ((a.z + e.z) + f.z) * (1.0f/3.0f);
            h = fmaf(w2v.x,xr.x, fmaf(w2v.y,xr.y, fmaf(w2v.z,xr.z, h))) + w2v.w;
            sA[kq*4+2][row] = h > 0.0f ? h : 0.0f;
            h = ((a.w + e.w) + f.w) * (1.0f/3.0f);
            h = fmaf(w3.x,xr.x, fmaf(w3.y,xr.y, fmaf(w3.z,xr.z, h))) + w3.w;
            sA[kq*4+3][row] = h > 0.0f ? h : 0.0f;
        }
        #pragma unroll
        for (int j = 0; j < 2; ++j) {   // w2 chunk: 128 outs x 4 kq slots
            int id = j * 256 + tid;
            int o  = id >> 2, kq = id & 3;
            float4 hh = ((const float4*)w2)[(size_t)o * 32 + kc * 4 + kq];
            sW[kq*4+0][o] = hh.x; sW[kq*4+1][o] = hh.y;
            sW[kq*4+2][o] = hh.z; sW[kq*4+3][o] = hh.w;
        }
        __syncthreads();
        #pragma unroll
        for (int kk = 0; kk < 16; ++kk) {
            float4 a0 = *(const float4*)&sA[kk][tr*8];
            float4 a1 = *(const float4*)&sA[kk][tr*8+4];
            float4 c0 = *(const float4*)&sW[kk][tc*4];
            float av[8] = {a0.x,a0.y,a0.z,a0.w,a1.x,a1.y,a1.z,a1.w};
            float bv[4] = {c0.x,c0.y,c0.z,c0.w};
            #pragma unroll
            for (int i = 0; i < 8; ++i)
                #pragma unroll
                for (int j = 0; j < 4; ++j)
                    acc[i][j] = fmaf(av[i], bv[j], acc[i][j]);
        }
        __syncthreads();
    }

    // ---- epilogue: bias + transposed store out[b][o][n] ----
    const int n0 = (row0 & (N_-1)) + tr*8;
    #pragma unroll
    for (int j = 0; j < 4; ++j) {
        int o = tc*4 + j;
        float bias = b2[o];
        float4 o0 = make_float4(acc[0][j]+bias, acc[1][j]+bias,
                                acc[2][j]+bias, acc[3][j]+bias);
        float4 o1 = make_float4(acc[4][j]+bias, acc[5][j]+bias,
                                acc[6][j]+bias, acc[7][j]+bias);
        float* dst = out + (((size_t)(b*OUT_ + o)) << 15) + n0;
        *(float4*)dst       = o0;
        *(float4*)(dst + 4) = o1;
    }
}

extern "C" void kernel_launch(void* const* d_in, const int* in_sizes, int n_in,
                              void* d_out, int out_size, void* d_ws, size_t ws_size,
                              hipStream_t stream) {
    const float* x        = (const float*)d_in[0];   // [B,N,3]
    const float* sx       = (const float*)d_in[1];   // [B,M,3]
    const float* features = (const float*)d_in[2];   // [B,M,C]
    const float* w1       = (const float*)d_in[3];   // [128,131]
    const float* b1       = (const float*)d_in[4];   // [128]
    const float* w2       = (const float*)d_in[5];   // [128,128]
    const float* b2       = (const float*)d_in[6];   // [128]
    float* out = (float*)d_out;                      // [B,128,N]

    char* ws = (char*)d_ws;
    // Layout:
    //   [2,6MB)     G        (4 MB)
    //   [33,49MB)   part_d   (16 MB)
    //   [49,57MB)   part_i   (8 MB, ushort4)
    float*   G      = (float*)  (ws + (2u  << 20));
    float4*  part_d = (float4*) (ws + (33u << 20));
    ushort4* part_i = (ushort4*)(ws + (33u << 20) + (16u<<20));

    fused_front_kernel<<<dim3(NNBLK + PREBLK), dim3(256), 0, stream>>>(x, sx, part_d, part_i,
                                                                      features, w1, G);
    fused_tail_kernel <<<dim3(NQ/QBLK), dim3(256), 0, stream>>>(part_d, part_i, G, x,
                                                                w1, b1, w2, b2, out);
}

// Round 9
// 230.177 us; speedup vs baseline: 1.0702x; 1.0702x over previous
//
#include <hip/hip_runtime.h>

#define B_   2
#define N_   32768
#define M_   4096
#define C_   128
#define OUT_ 128
#define IN_  131

#define NSPLIT 16
#define MCHUNK (M_ / NSPLIT)     // 256 points per split
#define NQ     (B_ * N_)         // 65536 total queries
#define NNBLK  ((NQ / 1024) * NSPLIT)   // 1024 NN blocks
#define PREBLK (B_ * M_ / 128)          // 64 pre-GEMM blocks
#define QBLK   64                       // tail queries per block

// ---------------------------------------------------------------------------
// K1 (fused front): REVERTED to round-5 exact form (scalar NN — v_pk_f32 has
// NO throughput advantage on CDNA4: 157.3 TF peak == scalar FMA rate; the
// packed experiment cost +17us). Blocks [0,1024) = split 3-NN; [1024,1088) =
// pre-GEMM. part_i ushort4.
// ---------------------------------------------------------------------------
#define NN_DECL(X)                                                        \
    float x0##X, x1##X, x2##X, xx##X;                                     \
    float bd0##X = 1e30f, bd1##X = 1e30f, bd2##X = 1e30f;                 \
    int   bi0##X = 0,     bi1##X = 0,     bi2##X = 0;

#define NN_LOAD(X, QQ) {                                                  \
    const int qi = q0 + (QQ) * 256 + t;                                   \
    x0##X = x[(size_t)qi*3+0];                                            \
    x1##X = x[(size_t)qi*3+1];                                            \
    x2##X = x[(size_t)qi*3+2];                                            \
    xx##X = __fadd_rn(__fadd_rn(__fmul_rn(x0##X,x0##X),                   \
                                __fmul_rn(x1##X,x1##X)),                  \
                      __fmul_rn(x2##X,x2##X)); }

#define NN_STEP(X) {                                                      \
    float dot = __fadd_rn(__fadd_rn(__fmul_rn(x0##X,s.x),                 \
                                    __fmul_rn(x1##X,s.y)),                \
                          __fmul_rn(x2##X,s.z));                          \
    float d2 = __fadd_rn(__fmaf_rn(-2.0f, dot, xx##X), s.w);              \
    const float k0 = bd0##X, k1 = bd1##X, k2 = bd2##X;                    \
    const bool c0 = d2 < k0, c1 = d2 < k1, c2 = d2 < k2;                  \
    bi2##X = c1 ? bi1##X : (c2 ? m : bi2##X);                             \
    bi1##X = c0 ? bi0##X : (c1 ? m : bi1##X);                             \
    bi0##X = c0 ? m : bi0##X;                                             \
    bd0##X = fminf(k0, d2);                                               \
    bd1##X = __builtin_amdgcn_fmed3f(d2, k0, k1);                         \
    bd2##X = __builtin_amdgcn_fmed3f(d2, k1, k2); }

#define NN_STORE(X, QQ) {                                                 \
    const int qi = q0 + (QQ) * 256 + t;                                   \
    part_d[(size_t)split * NQ + qi] =                                     \
        make_float4(bd0##X, bd1##X, bd2##X, 0.f);                         \
    part_i[(size_t)split * NQ + qi] =                                     \
        make_ushort4((unsigned short)bi0##X, (unsigned short)bi1##X,      \
                     (unsigned short)bi2##X, 0); }

__global__ __launch_bounds__(256, 4) void fused_front_kernel(const float* __restrict__ x,
                                                             const float* __restrict__ sx,
                                                             float4* __restrict__ part_d,
                                                             ushort4* __restrict__ part_i,
                                                             const float* __restrict__ features,
                                                             const float* __restrict__ w1,
                                                             float* __restrict__ G) {
    __shared__ float4 spts[MCHUNK];   // 4 KB   (NN path)
    __shared__ float  sI[16][132];    // 8.25 KB (pre path)
    __shared__ float  sW[16][132];    // 8.25 KB (pre path)
    const int tid = threadIdx.x;

    if (blockIdx.x < NNBLK) {
        // ---------------- NN path (byte-identical arithmetic) ----------------
        const int split = blockIdx.x & (NSPLIT - 1);
        const int qb    = blockIdx.x >> 4;
        const int q0    = qb * 1024;
        const int b     = q0 >> 15;                     // N_=32768
        const int t     = tid;

        {
            const float* sp = sx + ((size_t)b * M_ + split * MCHUNK + t) * 3;
            float s0 = sp[0], s1 = sp[1], s2 = sp[2];
            float ss = __fadd_rn(__fadd_rn(__fmul_rn(s0,s0), __fmul_rn(s1,s1)),
                                 __fmul_rn(s2,s2));
            spts[t] = make_float4(s0, s1, s2, ss);
        }
        __syncthreads();

        NN_DECL(A) NN_DECL(B) NN_DECL(C) NN_DECL(D)
        NN_LOAD(A, 0) NN_LOAD(B, 1) NN_LOAD(C, 2) NN_LOAD(D, 3)

        const int m_base = split * MCHUNK;
        #pragma unroll 2
        for (int j = 0; j < MCHUNK; ++j) {
            const float4 s = spts[j];
            const int m = m_base + j;
            NN_STEP(A) NN_STEP(B) NN_STEP(C) NN_STEP(D)
        }

        NN_STORE(A, 0) NN_STORE(B, 1) NN_STORE(C, 2) NN_STORE(D, 3)
    } else {
        // ---------------- pre-GEMM path (unchanged arithmetic) ---------------
        const int row0 = (blockIdx.x - NNBLK) * 128;
        const int tr   = tid & 15;
        const int tc   = tid >> 4;
        float acc[8][8] = {};

        for (int kc = 0; kc < 8; ++kc) {
            #pragma unroll
            for (int j = 0; j < 2; ++j) {
                int id  = j * 256 + tid;
                int row = id >> 2, kq = id & 3;
                float4 g = ((const float4*)features)[(size_t)(row0 + row) * 32 + kc * 4 + kq];
                sI[kq*4+0][row] = g.x; sI[kq*4+1][row] = g.y;
                sI[kq*4+2][row] = g.z; sI[kq*4+3][row] = g.w;
            }
            {
                int o = tid >> 1, kk0 = (tid & 1) * 8;
                #pragma unroll
                for (int kk = 0; kk < 8; ++kk)
                    sW[kk0+kk][o] = w1[(size_t)o * IN_ + 3 + kc*16 + kk0 + kk];
            }
            __syncthreads();
            #pragma unroll
            for (int kk = 0; kk < 16; ++kk) {
                float4 a0 = *(const float4*)&sI[kk][tr*8];
                float4 a1 = *(const float4*)&sI[kk][tr*8+4];
                float4 c0 = *(const float4*)&sW[kk][tc*8];
                float4 c1 = *(const float4*)&sW[kk][tc*8+4];
                float av[8] = {a0.x,a0.y,a0.z,a0.w,a1.x,a1.y,a1.z,a1.w};
                float bv[8] = {c0.x,c0.y,c0.z,c0.w,c1.x,c1.y,c1.z,c1.w};
                #pragma unroll
                for (int i = 0; i < 8; ++i)
                    #pragma unroll
                    for (int j = 0; j < 8; ++j)
                        acc[i][j] = fmaf(av[i], bv[j], acc[i][j]);
            }
            __syncthreads();
        }

        #pragma unroll
        for (int i = 0; i < 8; ++i) {
            int r = row0 + tr*8 + i;
            float4 o0 = make_float4(acc[i][0], acc[i][1], acc[i][2], acc[i][3]);
            float4 o1 = make_float4(acc[i][4], acc[i][5], acc[i][6], acc[i][7]);
            ((float4*)G)[(size_t)r * 32 + tc*2 + 0] = o0;
            ((float4*)G)[(size_t)r * 32 + tc*2 + 1] = o1;
        }
    }
}

// ---------------------------------------------------------------------------
// K3 (fused tail): round-5 structure, ONE isolated change — XCD-batch block
// swizzle. Default round-robin dispatch interleaves both batches on every
// XCD: the H-build's G gathers have an 8 MB working set vs the 4 MB per-XCD
// L2 -> thrash to L3 every chunk. Remap lb = ((bid&7)>>2)*512 + (bid>>3)*4
// + (bid&3) (bijective on [0,1024)): XCDs 0-3 serve batch 0, XCDs 4-7
// batch 1 -> per-XCD gather working set = 4 MB = one L2. Only the block->
// query mapping changes; all arithmetic byte-identical.
// ---------------------------------------------------------------------------
__global__ __launch_bounds__(256) void fused_tail_kernel(const float4* __restrict__ part_d,
                                                         const ushort4* __restrict__ part_i,
                                                         const float* __restrict__ G,
                                                         const float* __restrict__ x,
                                                         const float* __restrict__ w1,
                                                         const float* __restrict__ b1,
                                                         const float* __restrict__ w2,
                                                         const float* __restrict__ b2,
                                                         float* __restrict__ out) {
    __shared__ float  sA[16][68];     // H chunk [k][row]   4.25 KB
    __shared__ float  sW[16][132];    // w2 chunk [k][out]  8.25 KB
    __shared__ int4   sIdx[QBLK];     // merged top-3 per query
    __shared__ float4 sX[QBLK];       // query coords
    __shared__ float4 sWX[128];       // (wx0,wx1,wx2,b1) per channel

    // XCD-batch swizzle (assumes bid%8 round-robins XCDs; perf-only heuristic)
    const int bid  = blockIdx.x;
    const int lb   = ((bid & 7) >> 2) * 512 + (bid >> 3) * 4 + (bid & 3);
    const int row0 = lb * QBLK;

    const int tid  = threadIdx.x;
    const int tr   = tid & 7;         // row-group: rows tr*8 .. tr*8+7
    const int tc   = tid >> 3;        // col-group: cols tc*4 .. tc*4+3
    const int b    = row0 >> 15;

    // ---- Phase 0: merge (threads 0-63) || stage w1-xyz table (64-191) ----
    if (tid < QBLK) {
        const int q = row0 + tid;
        float b0 = 1e30f, b1v = 1e30f, b2v = 1e30f;
        int   i0 = 0,     i1 = 0,      i2 = 0;
        #pragma unroll
        for (int s = 0; s < NSPLIT; ++s) {
            float4  d = part_d[(size_t)s * NQ + q];
            ushort4 u = part_i[(size_t)s * NQ + q];
            const int ux = u.x, uy = u.y, uz = u.z;
            if (d.x < b2v) { if (d.x < b1v) { b2v=b1v; i2=i1;
                if (d.x < b0) { b1v=b0; i1=i0; b0=d.x; i0=ux; }
                else          { b1v=d.x; i1=ux; } } else { b2v=d.x; i2=ux; } }
            if (d.y < b2v) { if (d.y < b1v) { b2v=b1v; i2=i1;
                if (d.y < b0) { b1v=b0; i1=i0; b0=d.y; i0=uy; }
                else          { b1v=d.y; i1=uy; } } else { b2v=d.y; i2=uy; } }
            if (d.z < b2v) { if (d.z < b1v) { b2v=b1v; i2=i1;
                if (d.z < b0) { b1v=b0; i1=i0; b0=d.z; i0=uz; }
                else          { b1v=d.z; i1=uz; } } else { b2v=d.z; i2=uz; } }
        }
        sIdx[tid] = make_int4(i0, i1, i2, 0);
        const float* xp = x + (size_t)q * 3;
        sX[tid] = make_float4(xp[0], xp[1], xp[2], 0.f);
    } else if (tid < QBLK + 128) {
        const int c = tid - QBLK;
        sWX[c] = make_float4(w1[(size_t)c*IN_+0], w1[(size_t)c*IN_+1],
                             w1[(size_t)c*IN_+2], b1[c]);
    }
    __syncthreads();

    // ---- kc loop: build H chunk in LDS + stage w2 chunk, then FMA core ----
    const float4* gb = (const float4*)G + (size_t)b * M_ * 32;
    float acc[8][4] = {};
    for (int kc = 0; kc < 8; ++kc) {
        {   // H build: one (row, kq) slot per thread (row = tid>>2 in [0,64))
            const int row = tid >> 2, kq = tid & 3;
            const int c4 = kc * 4 + kq;          // channel-group [0,32)
            int4 v = sIdx[row];
            float4 a = gb[(size_t)v.x * 32 + c4];
            float4 e = gb[(size_t)v.y * 32 + c4];
            float4 f = gb[(size_t)v.z * 32 + c4];
            float4 xr = sX[row];
            float4 w0  = sWX[c4*4+0], w1v = sWX[c4*4+1];
            float4 w2v = sWX[c4*4+2], w3  = sWX[c4*4+3];
            float h;
            h = ((a.x + e.x) + f.x) * (1.0f/3.0f);
            h = fmaf(w0.x,xr.x, fmaf(w0.y,xr.y, fmaf(w0.z,xr.z, h))) + w0.w;
            sA[kq*4+0][row] = h > 0.0f ? h : 0.0f;
            h = ((a.y + e.y) + f.y) * (1.0f/3.0f);
            h = fmaf(w1v.x,xr.x, fmaf(w1v.y,xr.y, fmaf(w1v.z,xr.z, h))) + w1v.w;
            sA[kq*4+1][row] = h > 0.0f ? h : 0.0f;
            h = ((a.z + e.z) + f.z) * (1.0f/3.0f);
            h = fmaf(w2v.x,xr.x, fmaf(w2v.y,xr.y, fmaf(w2v.z,xr.z, h))) + w2v.w;
            sA[kq*4+2][row] = h > 0.0f ? h : 0.0f;
            h = ((a.w + e.w) + f.w) * (1.0f/3.0f);
            h = fmaf(w3.x,xr.x, fmaf(w3.y,xr.y, fmaf(w3.z,xr.z, h))) + w3.w;
            sA[kq*4+3][row] = h > 0.0f ? h : 0.0f;
        }
        #pragma unroll
        for (int j = 0; j < 2; ++j) {   // w2 chunk: 128 outs x 4 kq slots
            int id = j * 256 + tid;
            int o  = id >> 2, kq = id & 3;
            float4 hh = ((const float4*)w2)[(size_t)o * 32 + kc * 4 + kq];
            sW[kq*4+0][o] = hh.x; sW[kq*4+1][o] = hh.y;
            sW[kq*4+2][o] = hh.z; sW[kq*4+3][o] = hh.w;
        }
        __syncthreads();
        #pragma unroll
        for (int kk = 0; kk < 16; ++kk) {
            float4 a0 = *(const float4*)&sA[kk][tr*8];
            float4 a1 = *(const float4*)&sA[kk][tr*8+4];
            float4 c0 = *(const float4*)&sW[kk][tc*4];
            float av[8] = {a0.x,a0.y,a0.z,a0.w,a1.x,a1.y,a1.z,a1.w};
            float bv[4] = {c0.x,c0.y,c0.z,c0.w};
            #pragma unroll
            for (int i = 0; i < 8; ++i)
                #pragma unroll
                for (int j = 0; j < 4; ++j)
                    acc[i][j] = fmaf(av[i], bv[j], acc[i][j]);
        }
        __syncthreads();
    }

    // ---- epilogue: bias + transposed store out[b][o][n] ----
    const int n0 = (row0 & (N_-1)) + tr*8;
    #pragma unroll
    for (int j = 0; j < 4; ++j) {
        int o = tc*4 + j;
        float bias = b2[o];
        float4 o0 = make_float4(acc[0][j]+bias, acc[1][j]+bias,
                                acc[2][j]+bias, acc[3][j]+bias);
        float4 o1 = make_float4(acc[4][j]+bias, acc[5][j]+bias,
                                acc[6][j]+bias, acc[7][j]+bias);
        float* dst = out + (((size_t)(b*OUT_ + o)) << 15) + n0;
        *(float4*)dst       = o0;
        *(float4*)(dst + 4) = o1;
    }
}

extern "C" void kernel_launch(void* const* d_in, const int* in_sizes, int n_in,
                              void* d_out, int out_size, void* d_ws, size_t ws_size,
                              hipStream_t stream) {
    const float* x        = (const float*)d_in[0];   // [B,N,3]
    const float* sx       = (const float*)d_in[1];   // [B,M,3]
    const float* features = (const float*)d_in[2];   // [B,M,C]
    const float* w1       = (const float*)d_in[3];   // [128,131]
    const float* b1       = (const float*)d_in[4];   // [128]
    const float* w2       = (const float*)d_in[5];   // [128,128]
    const float* b2       = (const float*)d_in[6];   // [128]
    float* out = (float*)d_out;                      // [B,128,N]

    char* ws = (char*)d_ws;
    // Layout:
    //   [2,6MB)     G        (4 MB)
    //   [33,49MB)   part_d   (16 MB)
    //   [49,57MB)   part_i   (8 MB, ushort4)
    float*   G      = (float*)  (ws + (2u  << 20));
    float4*  part_d = (float4*) (ws + (33u << 20));
    ushort4* part_i = (ushort4*)(ws + (33u << 20) + (16u<<20));

    fused_front_kernel<<<dim3(NNBLK + PREBLK), dim3(256), 0, stream>>>(x, sx, part_d, part_i,
                                                                      features, w1, G);
    fused_tail_kernel <<<dim3(NQ/QBLK), dim3(256), 0, stream>>>(part_d, part_i, G, x,
                                                                w1, b1, w2, b2, out);
}